// Round 4
// baseline (223.582 us; speedup 1.0000x reference)
//
#include <hip/hip_runtime.h>

// Fused Bahdanau context-attention pooling, MI355X (gfx950).
//   K1 prep     : q = query@Wq^T (f32), Wk -> bf16 in ws, mask-layout flag
//   K2 main     : ONE WAVE per 16-row s-chunk, NO kv retention:
//                 A-frags packed f32->bf16 from global on the fly,
//                 k = kv@Wk^T via mfma_f32_16x16x32_bf16 (acc[8] = 32 VGPR),
//                 score = sum_a tanh(q+k)*Ws, in-wave softmax (m,d),
//                 context partial by RE-READING the chunk from L2 (hot).
//                 2 waves/block merge adjacent chunks -> per-32-row partials.
//   K3 combineA : per b: global M, D from 128 chunk (m,d); scl[j]
//   K4 combineB : context = sum_j scl_j*ctxp_j ; weights = exp(score-M)/D

typedef __attribute__((ext_vector_type(8))) short short8;
typedef __attribute__((ext_vector_type(4))) float f32x4;

#define S_LEN 4096
#define BATCH 32
#define KVD 512
#define AD 128
#define CHUNKS_PER_B 128               // 32-row groups per b
#define NPAIR (BATCH * CHUNKS_PER_B)   // 4096 blocks, 2 waves each

// ws byte offsets (same as R3, proven to fit)
#define FLAG_OFF   0
#define Q_OFF      1024
#define WK_OFF     17408       // + 128*512*2 = 131072
#define SCORES_OFF 148480      // + 32*4096*4 = 524288
#define MD_OFF     672768      // + 4096*2*4  = 32768
#define CTXP_OFF   705536      // + 4096*512*4 = 8388608
#define SCL_OFF    9094144     // + 32*128*4  = 16384
#define MD2_OFF    9110528     // + 32*2*4

__device__ __forceinline__ unsigned short f2bf_rne(float f) {
  unsigned int u = __float_as_uint(f);
  u = (u + 0x7FFFu + ((u >> 16) & 1u)) >> 16;
  return (unsigned short)u;
}
// round-half-up pack of 2 f32 -> 1 dword of 2 bf16 (lo, hi)
__device__ __forceinline__ unsigned int packbf(float a, float b) {
  unsigned int lo = __float_as_uint(a) + 0x8000u;
  unsigned int hi = __float_as_uint(b) + 0x8000u;
  return (lo >> 16) | (hi & 0xFFFF0000u);
}
__device__ __forceinline__ float tanh_fast(float x) {
  return 1.0f - 2.0f / (1.0f + __expf(2.0f * x));
}

__global__ __launch_bounds__(256) void prep_kernel(
    const float* __restrict__ query, const float* __restrict__ Wq,
    const float* __restrict__ Wk, const void* __restrict__ maskp,
    float* __restrict__ qws, unsigned short* __restrict__ wkb,
    int* __restrict__ flagp) {
  int blk = blockIdx.x, t = threadIdx.x;
  if (blk < 32) {
    __shared__ float qrow[KVD];
    qrow[t] = query[blk * KVD + t];
    qrow[t + 256] = query[blk * KVD + t + 256];
    __syncthreads();
    int a = t >> 1, half = t & 1;
    const float4* wq4 = (const float4*)(Wq + (size_t)a * KVD + half * 256);
    const float4* qr4 = (const float4*)(qrow + half * 256);
    float s = 0.f;
#pragma unroll 8
    for (int i = 0; i < 64; ++i) {
      float4 wv = wq4[i], qv = qr4[i];
      s += wv.x * qv.x + wv.y * qv.y + wv.z * qv.z + wv.w * qv.w;
    }
    s += __shfl_xor(s, 1);
    if (half == 0) qws[blk * AD + a] = s;
  } else if (blk < 40) {
    int j = blk - 32;
    const float4* src = (const float4*)Wk;
#pragma unroll 4
    for (int i = 0; i < 8; ++i) {
      int idx4 = j * 2048 + i * 256 + t;
      float4 v = src[idx4];
      ushort4 o;
      o.x = f2bf_rne(v.x); o.y = f2bf_rne(v.y);
      o.z = f2bf_rne(v.z); o.w = f2bf_rne(v.w);
      ((ushort4*)wkb)[idx4] = o;
    }
  } else {
    __shared__ int okv;
    if (t == 0) okv = 1;
    __syncthreads();
    if (t < 128) {
      int wv = ((const int*)maskp)[t];
      if (!(wv == 0 || wv == 1)) okv = 0;
    }
    __syncthreads();
    if (t == 0) flagp[0] = okv;  // 1 = int32 layout, 0 = byte layout
  }
}

__global__ __launch_bounds__(128) void main_kernel(
    const float* __restrict__ kv, const void* __restrict__ maskp,
    const float* __restrict__ Ws, const float* __restrict__ qws,
    const unsigned short* __restrict__ wkb, const int* __restrict__ flagp,
    float* __restrict__ scores, float* __restrict__ md,
    float* __restrict__ ctxp) {
  int t = threadIdx.x;
  int lane = t & 63, wave = t >> 6;
  int g2 = blockIdx.x;                 // 32-row group id
  int b = g2 >> 7, pr = g2 & (CHUNKS_PER_B - 1);
  int s0 = pr * 32 + wave * 16;        // this wave's 16 rows
  int lr = lane & 15, lg = lane >> 4;

  __shared__ float mrg[KVD];           // 2 KB merge buffer
  __shared__ float mdsh[2][2];
  __shared__ float escf[2][16];

  // early loads
  int flag = flagp[0];
  int mload = 0;
  if (lane < 16) {
    int gs = b * S_LEN + s0 + lane;
    mload = flag ? ((const int*)maskp)[gs]
                 : (int)((const unsigned char*)maskp)[gs];
  }
  float qv[8], wv[8];
#pragma unroll
  for (int n = 0; n < 8; ++n) {
    qv[n] = qws[b * AD + n * 16 + lr];
    wv[n] = Ws[n * 16 + lr];
  }

  // ---- projection: C[s(16)][a(128)] = kv @ Wk^T, A from global f32 ----
  f32x4 acc[8];
#pragma unroll
  for (int n = 0; n < 8; ++n) acc[n] = (f32x4)0.f;

  const float* arow = kv + ((size_t)b * S_LEN + s0 + lr) * KVD + lg * 8;
  const unsigned short* brow = wkb + (size_t)lr * KVD + lg * 8;

#pragma unroll 2
  for (int kk = 0; kk < KVD / 32; ++kk) {
    float4 alo = *(const float4*)(arow + kk * 32);
    float4 ahi = *(const float4*)(arow + kk * 32 + 4);
    short8 af;
    ((unsigned int*)&af)[0] = packbf(alo.x, alo.y);
    ((unsigned int*)&af)[1] = packbf(alo.z, alo.w);
    ((unsigned int*)&af)[2] = packbf(ahi.x, ahi.y);
    ((unsigned int*)&af)[3] = packbf(ahi.z, ahi.w);
#pragma unroll
    for (int n = 0; n < 8; ++n) {
      short8 bf = *(const short8*)(brow + (size_t)n * 16 * KVD + kk * 32);
      acc[n] = __builtin_amdgcn_mfma_f32_16x16x32_bf16(af, bf, acc[n], 0, 0, 0);
    }
  }

  // ---- scores: D layout col a = 16n+lr, row s = 4lg+reg ----
  float sc[4];
#pragma unroll
  for (int reg = 0; reg < 4; ++reg) {
    float v = 0.f;
#pragma unroll
    for (int n = 0; n < 8; ++n)
      v += tanh_fast(qv[n] + acc[n][reg]) * wv[n];
    v += __shfl_xor(v, 1);
    v += __shfl_xor(v, 2);
    v += __shfl_xor(v, 4);
    v += __shfl_xor(v, 8);
    int row = 4 * lg + reg;
    int mk = __shfl(mload, row);
    sc[reg] = mk ? v : -INFINITY;
  }

  // ---- in-wave softmax over 16 rows ----
  float m = fmaxf(fmaxf(sc[0], sc[1]), fmaxf(sc[2], sc[3]));
  m = fmaxf(m, __shfl_xor(m, 16));
  m = fmaxf(m, __shfl_xor(m, 32));
  float e[4], d = 0.f;
#pragma unroll
  for (int reg = 0; reg < 4; ++reg) {
    e[reg] = (sc[reg] == -INFINITY) ? 0.f : __expf(sc[reg] - m);
    d += e[reg];
  }
  d += __shfl_xor(d, 16);
  d += __shfl_xor(d, 32);

  if (lr == 0) {
#pragma unroll
    for (int reg = 0; reg < 4; ++reg) {
      escf[wave][4 * lg + reg] = e[reg];
      scores[b * S_LEN + s0 + 4 * lg + reg] = sc[reg];
    }
  }
  if (lane == 0) { mdsh[wave][0] = m; mdsh[wave][1] = d; }

  // ---- context partial: re-read own chunk from L2, c = lane*8..+7 ----
  float4 c0 = make_float4(0.f, 0.f, 0.f, 0.f);
  float4 c1 = make_float4(0.f, 0.f, 0.f, 0.f);
  const float* kvc = kv + ((size_t)b * S_LEN + s0) * KVD + lane * 8;
#pragma unroll 4
  for (int s = 0; s < 16; ++s) {
    float ev = escf[wave][s];
    float4 v0 = *(const float4*)(kvc + (size_t)s * KVD);
    float4 v1 = *(const float4*)(kvc + (size_t)s * KVD + 4);
    c0.x += ev * v0.x; c0.y += ev * v0.y; c0.z += ev * v0.z; c0.w += ev * v0.w;
    c1.x += ev * v1.x; c1.y += ev * v1.y; c1.z += ev * v1.z; c1.w += ev * v1.w;
  }

  __syncthreads();  // mdsh visible to both waves
  float m0 = mdsh[0][0], d0 = mdsh[0][1];
  float m1 = mdsh[1][0], d1 = mdsh[1][1];
  float M = fmaxf(m0, m1);
  float scl0 = (d0 > 0.f) ? __expf(m0 - M) : 0.f;
  float scl1 = (d1 > 0.f) ? __expf(m1 - M) : 0.f;
  float D = scl0 * d0 + scl1 * d1;

  if (wave == 0) {
    float4 w0, w1;
    w0.x = scl0 * c0.x; w0.y = scl0 * c0.y; w0.z = scl0 * c0.z; w0.w = scl0 * c0.w;
    w1.x = scl0 * c1.x; w1.y = scl0 * c1.y; w1.z = scl0 * c1.z; w1.w = scl0 * c1.w;
    *(float4*)&mrg[lane * 8] = w0;
    *(float4*)&mrg[lane * 8 + 4] = w1;
  }
  __syncthreads();
  if (wave == 1) {
    float4 r0 = *(const float4*)&mrg[lane * 8];
    float4 r1 = *(const float4*)&mrg[lane * 8 + 4];
    r0.x += scl1 * c0.x; r0.y += scl1 * c0.y; r0.z += scl1 * c0.z; r0.w += scl1 * c0.w;
    r1.x += scl1 * c1.x; r1.y += scl1 * c1.y; r1.z += scl1 * c1.z; r1.w += scl1 * c1.w;
    float* cp = ctxp + (size_t)g2 * KVD + lane * 8;
    *(float4*)cp = r0;
    *(float4*)(cp + 4) = r1;
    if (lane == 0) {
      md[g2 * 2] = (D > 0.f) ? M : -INFINITY;
      md[g2 * 2 + 1] = D;
    }
  }
}

__global__ __launch_bounds__(128) void combineA_kernel(
    const float* __restrict__ md, float* __restrict__ scl,
    float* __restrict__ md2) {
  int b = blockIdx.x, t = threadIdx.x;  // 128 threads = 2 waves
  float mv = md[(b * CHUNKS_PER_B + t) * 2];
  float dv = md[(b * CHUNKS_PER_B + t) * 2 + 1];
  __shared__ float rmax[2], rsum[2];
  float m = mv;
  m = fmaxf(m, __shfl_xor(m, 1));
  m = fmaxf(m, __shfl_xor(m, 2));
  m = fmaxf(m, __shfl_xor(m, 4));
  m = fmaxf(m, __shfl_xor(m, 8));
  m = fmaxf(m, __shfl_xor(m, 16));
  m = fmaxf(m, __shfl_xor(m, 32));
  if ((t & 63) == 0) rmax[t >> 6] = m;
  __syncthreads();
  float M = fmaxf(rmax[0], rmax[1]);
  float e = (dv > 0.f) ? __expf(mv - M) : 0.f;
  float pd = e * dv;
  pd += __shfl_xor(pd, 1);
  pd += __shfl_xor(pd, 2);
  pd += __shfl_xor(pd, 4);
  pd += __shfl_xor(pd, 8);
  pd += __shfl_xor(pd, 16);
  pd += __shfl_xor(pd, 32);
  if ((t & 63) == 0) rsum[t >> 6] = pd;
  __syncthreads();
  float D = rsum[0] + rsum[1];
  float invD = 1.f / D;
  scl[b * CHUNKS_PER_B + t] = e * invD;
  if (t == 0) { md2[b * 2] = M; md2[b * 2 + 1] = invD; }
}

__global__ __launch_bounds__(256) void combineB_kernel(
    const float* __restrict__ scl, const float* __restrict__ md2,
    const float* __restrict__ ctxp, const float* __restrict__ scores,
    float* __restrict__ out) {
  int strip = blockIdx.x, b = blockIdx.y, t = threadIdx.x;
  if (strip < 8) {
    __shared__ float part[4][64];
    int c = strip * 64 + (t & 63);
    int jg = t >> 6;
    float sum = 0.f;
    for (int j = jg; j < CHUNKS_PER_B; j += 4)
      sum += scl[b * CHUNKS_PER_B + j] *
             ctxp[(size_t)(b * CHUNKS_PER_B + j) * KVD + c];
    part[jg][t & 63] = sum;
    __syncthreads();
    if (t < 64)
      out[b * KVD + c] = part[0][t] + part[1][t] + part[2][t] + part[3][t];
  } else {
    float M = md2[b * 2], invD = md2[b * 2 + 1];
    int sbase = (strip - 8) * 1024;
#pragma unroll
    for (int i = 0; i < 4; ++i) {
      int s = sbase + i * 256 + t;
      float scv = scores[b * S_LEN + s];
      out[BATCH * KVD + b * S_LEN + s] = __expf(scv - M) * invD;  // -inf -> 0
    }
  }
}

extern "C" void kernel_launch(void* const* d_in, const int* in_sizes, int n_in,
                              void* d_out, int out_size, void* d_ws, size_t ws_size,
                              hipStream_t stream) {
  const float* query = (const float*)d_in[0];
  const float* kv    = (const float*)d_in[1];
  const void*  maskp = d_in[2];
  const float* Wq    = (const float*)d_in[3];
  const float* Wk    = (const float*)d_in[4];
  const float* Ws    = (const float*)d_in[5];
  float* out = (float*)d_out;
  char* w = (char*)d_ws;
  int* flagp = (int*)(w + FLAG_OFF);
  float* qws = (float*)(w + Q_OFF);
  unsigned short* wkb = (unsigned short*)(w + WK_OFF);
  float* scores = (float*)(w + SCORES_OFF);
  float* md = (float*)(w + MD_OFF);
  float* ctxp = (float*)(w + CTXP_OFF);
  float* scl = (float*)(w + SCL_OFF);
  float* md2 = (float*)(w + MD2_OFF);

  prep_kernel<<<41, 256, 0, stream>>>(query, Wq, Wk, maskp, qws, wkb, flagp);
  main_kernel<<<NPAIR, 128, 0, stream>>>(kv, maskp, Ws, qws, wkb, flagp,
                                         scores, md, ctxp);
  combineA_kernel<<<BATCH, 128, 0, stream>>>(md, scl, md2);
  combineB_kernel<<<dim3(12, BATCH), 256, 0, stream>>>(scl, md2, ctxp, scores, out);
}

// Round 5
// 162.968 us; speedup vs baseline: 1.3719x; 1.3719x over previous
//
#include <hip/hip_runtime.h>

// Fused Bahdanau context-attention pooling, MI355X (gfx950).
//   K1 prep     : q = query@Wq^T (f32), Wk -> bf16 in ws, mask-layout flag
//   K2 main     : block = 256 thr, 64-row kv tile:
//                 stage 128KB f32 -> XOR-swizzled bf16 LDS with DEEP batches
//                 (8 independent float4 loads/thread back-to-back),
//                 per-wave 16-row projection (mfma 16x16x32 bf16, A from LDS,
//                 B = L2-hot Wk), in-wave score tanh(q+k)*Ws + softmax (m,d),
//                 block context phase from LDS tile with per-wave rescale.
//                 kv touches HBM exactly once. 2 barriers.
//   K3 combineA : per b: global M, D over 64 group (m,d); scl[j]
//   K4 combineB : context = sum_j scl_j*ctxp_j ; weights = exp(score-M)/D

typedef __attribute__((ext_vector_type(8))) short short8;
typedef __attribute__((ext_vector_type(4))) float f32x4;

#define S_LEN 4096
#define BATCH 32
#define KVD 512
#define AD 128
#define GRP 64                          // rows per block
#define GRPS_PER_B (S_LEN / GRP)        // 64
#define NBLK (BATCH * GRPS_PER_B)       // 2048

// ws byte offsets
#define FLAG_OFF   0
#define Q_OFF      1024
#define WK_OFF     17408       // + 128*512*2 = 131072
#define SCORES_OFF 148480      // + 32*4096*4 = 524288
#define MD_OFF     672768      // + 2048*2*4  = 16384
#define CTXP_OFF   705536      // + 2048*512*4 = 4194304
#define SCL_OFF    9094144     // + 32*64*4   = 8192
#define MD2_OFF    9110528     // + 32*2*4

__device__ __forceinline__ unsigned short f2bf_rne(float f) {
  unsigned int u = __float_as_uint(f);
  u = (u + 0x7FFFu + ((u >> 16) & 1u)) >> 16;
  return (unsigned short)u;
}
// round-half-up pack of 2 f32 -> 1 dword of 2 bf16 (lo, hi)
__device__ __forceinline__ unsigned int packbf(float a, float b) {
  unsigned int lo = __float_as_uint(a) + 0x8000u;
  unsigned int hi = __float_as_uint(b) + 0x8000u;
  return (lo >> 16) | (hi & 0xFFFF0000u);
}
__device__ __forceinline__ float tanh_fast(float x) {
  return 1.0f - 2.0f / (1.0f + __expf(2.0f * x));
}

__global__ __launch_bounds__(256) void prep_kernel(
    const float* __restrict__ query, const float* __restrict__ Wq,
    const float* __restrict__ Wk, const void* __restrict__ maskp,
    float* __restrict__ qws, unsigned short* __restrict__ wkb,
    int* __restrict__ flagp) {
  int blk = blockIdx.x, t = threadIdx.x;
  if (blk < 32) {
    __shared__ float qrow[KVD];
    qrow[t] = query[blk * KVD + t];
    qrow[t + 256] = query[blk * KVD + t + 256];
    __syncthreads();
    int a = t >> 1, half = t & 1;
    const float4* wq4 = (const float4*)(Wq + (size_t)a * KVD + half * 256);
    const float4* qr4 = (const float4*)(qrow + half * 256);
    float s = 0.f;
#pragma unroll 8
    for (int i = 0; i < 64; ++i) {
      float4 wv = wq4[i], qv = qr4[i];
      s += wv.x * qv.x + wv.y * qv.y + wv.z * qv.z + wv.w * qv.w;
    }
    s += __shfl_xor(s, 1);
    if (half == 0) qws[blk * AD + a] = s;
  } else if (blk < 40) {
    int j = blk - 32;
    const float4* src = (const float4*)Wk;
#pragma unroll 4
    for (int i = 0; i < 8; ++i) {
      int idx4 = j * 2048 + i * 256 + t;
      float4 v = src[idx4];
      ushort4 o;
      o.x = f2bf_rne(v.x); o.y = f2bf_rne(v.y);
      o.z = f2bf_rne(v.z); o.w = f2bf_rne(v.w);
      ((ushort4*)wkb)[idx4] = o;
    }
  } else {
    __shared__ int okv;
    if (t == 0) okv = 1;
    __syncthreads();
    if (t < 128) {
      int wv = ((const int*)maskp)[t];
      if (!(wv == 0 || wv == 1)) okv = 0;
    }
    __syncthreads();
    if (t == 0) flagp[0] = okv;  // 1 = int32 layout, 0 = byte layout
  }
}

__global__ __launch_bounds__(256) void main_kernel(
    const float* __restrict__ kv, const void* __restrict__ maskp,
    const float* __restrict__ Ws, const float* __restrict__ qws,
    const unsigned short* __restrict__ wkb, const int* __restrict__ flagp,
    float* __restrict__ scores, float* __restrict__ md,
    float* __restrict__ ctxp) {
  int t = threadIdx.x;
  int lane = t & 63, wave = t >> 6;
  int g = blockIdx.x;                   // 64-row group id
  int b = g >> 6;
  int s0w = (g & 63) * GRP + wave * 16; // this wave's 16 rows (within b)
  int lr = lane & 15, lg = lane >> 4;

  __shared__ char tileb[GRP * 1024];    // 64 rows x 512 bf16, XOR-swizzled
  __shared__ float escf[GRP];
  __shared__ float mdsh[4][2];

  // early small loads (L2), overlap with staging
  int flag = flagp[0];
  int mload = 0;
  if (lane < 16) {
    int gs = b * S_LEN + s0w + lane;
    mload = flag ? ((const int*)maskp)[gs]
                 : (int)((const unsigned char*)maskp)[gs];
  }
  float qv[8], wv[8];
#pragma unroll
  for (int n = 0; n < 8; ++n) {
    qv[n] = qws[b * AD + n * 16 + lr];
    wv[n] = Ws[n * 16 + lr];
  }

  // ---- stage: 64 rows x 512 f32 (contiguous 128KB) -> swizzled bf16 LDS ----
  // 8192 float4s; 4 batches of 8 back-to-back loads per thread (deep MLP).
  const float4* src4 = (const float4*)(kv + (size_t)g * GRP * KVD);
#pragma unroll 1
  for (int i = 0; i < 4; ++i) {
    float4 v[8];
#pragma unroll
    for (int j = 0; j < 8; ++j) v[j] = src4[i * 2048 + j * 256 + t];
#pragma unroll
    for (int j = 0; j < 8; ++j) {
      int f = i * 2048 + j * 256 + t;
      int r = f >> 7, c4 = f & 127;     // row, float4-col
      uint2 w;
      w.x = packbf(v[j].x, v[j].y);
      w.y = packbf(v[j].z, v[j].w);
      *(uint2*)(tileb + ((r * 1024 + c4 * 8) ^ ((r & 7) << 4))) = w;
    }
  }
  __syncthreads();

  // ---- per-wave projection: C[s(16)][a(128)] = kv @ Wk^T ----
  f32x4 acc[8];
#pragma unroll
  for (int n = 0; n < 8; ++n) acc[n] = (f32x4)0.f;

  const unsigned short* brow = wkb + (size_t)lr * KVD + lg * 8;
  const char* ta = tileb + (wave * 16 + lr) * 1024;  // (16w+lr)&7 == lr&7
  int axor = (lr & 7) << 4;

  for (int kk = 0; kk < KVD / 32; ++kk) {
    short8 af = *(const short8*)(ta + ((kk * 64 + lg * 16) ^ axor));
#pragma unroll
    for (int n = 0; n < 8; ++n) {
      short8 bf = *(const short8*)(brow + (size_t)n * 16 * KVD + kk * 32);
      acc[n] = __builtin_amdgcn_mfma_f32_16x16x32_bf16(af, bf, acc[n], 0, 0, 0);
    }
  }

  // ---- scores: D layout col a = 16n+lr, row s = 4lg+reg ----
  float sc[4];
#pragma unroll
  for (int reg = 0; reg < 4; ++reg) {
    float v = 0.f;
#pragma unroll
    for (int n = 0; n < 8; ++n)
      v += tanh_fast(qv[n] + acc[n][reg]) * wv[n];
    v += __shfl_xor(v, 1);
    v += __shfl_xor(v, 2);
    v += __shfl_xor(v, 4);
    v += __shfl_xor(v, 8);
    int row = 4 * lg + reg;
    int mk = __shfl(mload, row);
    sc[reg] = mk ? v : -INFINITY;
  }

  // ---- in-wave softmax over 16 rows ----
  float m = fmaxf(fmaxf(sc[0], sc[1]), fmaxf(sc[2], sc[3]));
  m = fmaxf(m, __shfl_xor(m, 16));
  m = fmaxf(m, __shfl_xor(m, 32));
  float e[4], d = 0.f;
#pragma unroll
  for (int reg = 0; reg < 4; ++reg) {
    e[reg] = (sc[reg] == -INFINITY) ? 0.f : __expf(sc[reg] - m);
    d += e[reg];
  }
  d += __shfl_xor(d, 16);
  d += __shfl_xor(d, 32);

  if (lr == 0) {
#pragma unroll
    for (int reg = 0; reg < 4; ++reg) {
      int row = 4 * lg + reg;
      escf[wave * 16 + row] = e[reg];
      scores[b * S_LEN + s0w + row] = sc[reg];
    }
  }
  if (lane == 0) { mdsh[wave][0] = m; mdsh[wave][1] = d; }
  __syncthreads();

  // ---- block context: ctx[c] = sum_w scl_w sum_{s in w} e_s kv[s][c] ----
  float m0 = mdsh[0][0], m1 = mdsh[1][0], m2 = mdsh[2][0], m3 = mdsh[3][0];
  float d0 = mdsh[0][1], d1 = mdsh[1][1], d2 = mdsh[2][1], d3 = mdsh[3][1];
  float M = fmaxf(fmaxf(m0, m1), fmaxf(m2, m3));
  float sl[4];
  sl[0] = (d0 > 0.f) ? __expf(m0 - M) : 0.f;
  sl[1] = (d1 > 0.f) ? __expf(m1 - M) : 0.f;
  sl[2] = (d2 > 0.f) ? __expf(m2 - M) : 0.f;
  sl[3] = (d3 > 0.f) ? __expf(m3 - M) : 0.f;
  float D = sl[0] * d0 + sl[1] * d1 + sl[2] * d2 + sl[3] * d3;

  // thread t owns cols 2t, 2t+1 (one dword per row)
  float c0 = 0.f, c1 = 0.f;
#pragma unroll 4
  for (int s = 0; s < GRP; ++s) {
    float ev = escf[s] * sl[s >> 4];
    unsigned int u = *(const unsigned int*)(tileb + ((s * 1024 + 4 * t) ^ ((s & 7) << 4)));
    c0 += ev * __uint_as_float(u << 16);
    c1 += ev * __uint_as_float(u & 0xFFFF0000u);
  }
  float2 cw; cw.x = c0; cw.y = c1;
  *(float2*)(ctxp + (size_t)g * KVD + 2 * t) = cw;
  if (t == 0) {
    md[g * 2] = (D > 0.f) ? M : -INFINITY;
    md[g * 2 + 1] = D;
  }
}

__global__ __launch_bounds__(64) void combineA_kernel(
    const float* __restrict__ md, float* __restrict__ scl,
    float* __restrict__ md2) {
  int b = blockIdx.x, t = threadIdx.x;  // 64 threads = 1 wave
  float mv = md[(b * GRPS_PER_B + t) * 2];
  float dv = md[(b * GRPS_PER_B + t) * 2 + 1];
  float m = mv;
  m = fmaxf(m, __shfl_xor(m, 1));
  m = fmaxf(m, __shfl_xor(m, 2));
  m = fmaxf(m, __shfl_xor(m, 4));
  m = fmaxf(m, __shfl_xor(m, 8));
  m = fmaxf(m, __shfl_xor(m, 16));
  m = fmaxf(m, __shfl_xor(m, 32));
  float M = m;
  float e = (dv > 0.f) ? __expf(mv - M) : 0.f;
  float pd = e * dv;
  pd += __shfl_xor(pd, 1);
  pd += __shfl_xor(pd, 2);
  pd += __shfl_xor(pd, 4);
  pd += __shfl_xor(pd, 8);
  pd += __shfl_xor(pd, 16);
  pd += __shfl_xor(pd, 32);
  float D = pd;
  float invD = 1.f / D;
  scl[b * GRPS_PER_B + t] = e * invD;
  if (t == 0) { md2[b * 2] = M; md2[b * 2 + 1] = invD; }
}

__global__ __launch_bounds__(256) void combineB_kernel(
    const float* __restrict__ scl, const float* __restrict__ md2,
    const float* __restrict__ ctxp, const float* __restrict__ scores,
    float* __restrict__ out) {
  int strip = blockIdx.x, b = blockIdx.y, t = threadIdx.x;
  if (strip < 8) {
    __shared__ float part[4][64];
    int c = strip * 64 + (t & 63);
    int jg = t >> 6;
    float sum = 0.f;
    for (int j = jg; j < GRPS_PER_B; j += 4)
      sum += scl[b * GRPS_PER_B + j] *
             ctxp[(size_t)(b * GRPS_PER_B + j) * KVD + c];
    part[jg][t & 63] = sum;
    __syncthreads();
    if (t < 64)
      out[b * KVD + c] = part[0][t] + part[1][t] + part[2][t] + part[3][t];
  } else {
    float M = md2[b * 2], invD = md2[b * 2 + 1];
    int sbase = (strip - 8) * 1024;
#pragma unroll
    for (int i = 0; i < 4; ++i) {
      int s = sbase + i * 256 + t;
      float scv = scores[b * S_LEN + s];
      out[BATCH * KVD + b * S_LEN + s] = __expf(scv - M) * invD;  // -inf -> 0
    }
  }
}

extern "C" void kernel_launch(void* const* d_in, const int* in_sizes, int n_in,
                              void* d_out, int out_size, void* d_ws, size_t ws_size,
                              hipStream_t stream) {
  const float* query = (const float*)d_in[0];
  const float* kv    = (const float*)d_in[1];
  const void*  maskp = d_in[2];
  const float* Wq    = (const float*)d_in[3];
  const float* Wk    = (const float*)d_in[4];
  const float* Ws    = (const float*)d_in[5];
  float* out = (float*)d_out;
  char* w = (char*)d_ws;
  int* flagp = (int*)(w + FLAG_OFF);
  float* qws = (float*)(w + Q_OFF);
  unsigned short* wkb = (unsigned short*)(w + WK_OFF);
  float* scores = (float*)(w + SCORES_OFF);
  float* md = (float*)(w + MD_OFF);
  float* ctxp = (float*)(w + CTXP_OFF);
  float* scl = (float*)(w + SCL_OFF);
  float* md2 = (float*)(w + MD2_OFF);

  prep_kernel<<<41, 256, 0, stream>>>(query, Wq, Wk, maskp, qws, wkb, flagp);
  main_kernel<<<NBLK, 256, 0, stream>>>(kv, maskp, Ws, qws, wkb, flagp,
                                        scores, md, ctxp);
  combineA_kernel<<<BATCH, 64, 0, stream>>>(md, scl, md2);
  combineB_kernel<<<dim3(12, BATCH), 256, 0, stream>>>(scl, md2, ctxp, scores, out);
}